// Round 4
// baseline (903.165 us; speedup 1.0000x reference)
//
#include <hip/hip_runtime.h>
#include <cstdint>
#include <cstddef>

// Problem constants (match reference setup_inputs)
#define Bb   256
#define Tt   250
#define DIN  700
#define Hh   128
#define DOUT 20

// ---------------------------------------------------------------------------
// Phase 1: H1[b*T+t][h] = x[b][t][:] @ W1[:,h] + b1[h]
// M=64000, K=700, N=128. 128x128 tile, BK=20, 256 threads, 8x8 micro-tile.
// Bs column groups XOR-swizzled (pg = g ^ (g>>3)): the compute-loop B reads
// (16 lanes at float offsets tx*8 -> 4-way bank conflict) become exactly
// 2-way (= free). Swizzle is a bijection on groups so staging cost unchanged.
// ---------------------------------------------------------------------------
constexpr int BM  = 128;
constexpr int BK  = 20;
constexpr int BN  = 128;
constexpr int BMP = BM + 4;   // padded row length for Ast (staging writes)

__device__ __forceinline__ int bswz(int g) { return g ^ (g >> 3); }

__global__ __launch_bounds__(256, 2) void gemm_h1(const float* __restrict__ x,
                                                  const float* __restrict__ W1,
                                                  const float* __restrict__ b1,
                                                  float* __restrict__ H1) {
    __shared__ float Ast[BK][BMP];  // x tile, TRANSPOSED: Ast[k][m], padded
    __shared__ float Bs[BK][BN];    // W1 tile, column-group swizzled

    const int tid = threadIdx.x;
    const int tx  = tid & 15;       // col group: cols tx*8 .. +7
    const int ty  = tid >> 4;       // row group: rows ty*8 .. +7
    const int m0  = blockIdx.x * BM;

    // swizzled float offsets of this thread's two B column quads
    const int c0 = bswz(tx * 2) * 4;
    const int c1 = bswz(tx * 2 + 1) * 4;

    float acc[8][8];
#pragma unroll
    for (int r = 0; r < 8; ++r)
#pragma unroll
        for (int c = 0; c < 8; ++c) acc[r][c] = 0.f;

    for (int k0 = 0; k0 < DIN; k0 += BK) {
        // Stage A: 128 rows x 20 k = 640 float4 (coalesced global read,
        // scattered LDS writes, +4 pad keeps them ~conflict-light).
#pragma unroll
        for (int idx = tid; idx < 640; idx += 256) {
            int row = idx / 5;
            int kq  = (idx - row * 5) * 4;
            const float4 v =
                *(const float4*)&x[(size_t)(m0 + row) * DIN + (k0 + kq)];
            Ast[kq + 0][row] = v.x;
            Ast[kq + 1][row] = v.y;
            Ast[kq + 2][row] = v.z;
            Ast[kq + 3][row] = v.w;
        }
        // Stage B: 20 rows x 32 column-groups, swizzled placement.
#pragma unroll
        for (int idx = tid; idx < 640; idx += 256) {
            int kr = idx >> 5;
            int g  = idx & 31;
            *(float4*)&Bs[kr][bswz(g) * 4] =
                *(const float4*)&W1[(size_t)(k0 + kr) * BN + g * 4];
        }
        __syncthreads();

#pragma unroll
        for (int kk = 0; kk < BK; ++kk) {
            float a[8], bv[8];
            *(float4*)&a[0]  = *(const float4*)&Ast[kk][ty * 8];
            *(float4*)&a[4]  = *(const float4*)&Ast[kk][ty * 8 + 4];
            *(float4*)&bv[0] = *(const float4*)&Bs[kk][c0];
            *(float4*)&bv[4] = *(const float4*)&Bs[kk][c1];
#pragma unroll
            for (int r = 0; r < 8; ++r)
#pragma unroll
                for (int c = 0; c < 8; ++c)
                    acc[r][c] = fmaf(a[r], bv[c], acc[r][c]);
        }
        __syncthreads();
    }

    float bb[8];
#pragma unroll
    for (int c = 0; c < 8; ++c) bb[c] = b1[tx * 8 + c];

#pragma unroll
    for (int r = 0; r < 8; ++r) {
        size_t row = (size_t)(m0 + ty * 8 + r);
        float4 o0, o1;
        o0.x = acc[r][0] + bb[0]; o0.y = acc[r][1] + bb[1];
        o0.z = acc[r][2] + bb[2]; o0.w = acc[r][3] + bb[3];
        o1.x = acc[r][4] + bb[4]; o1.y = acc[r][5] + bb[5];
        o1.z = acc[r][6] + bb[6]; o1.w = acc[r][7] + bb[7];
        *(float4*)&H1[row * Hh + tx * 8]     = o0;
        *(float4*)&H1[row * Hh + tx * 8 + 4] = o1;
    }
}

// ---------------------------------------------------------------------------
// Phase 2: recurrence, wave-autonomous (256 blocks x 64 threads, lane owns
// units {lane, lane+64}). Per step, ONE pipelined sequence:
//   LIF1 -> extract16(M1) -> issue W2(LDS b64) + rcW1(global, saddr) loads
//   -> lgkm wait (LDS only!) -> W2 FMAs -> LIF2 -> extract16(M2)
//   -> issue rcW2(LDS) -> lgkm wait -> rcW2 FMAs
//   -> consume deferred rcW1 regs (vmcnt wait lands here, ~600cyc after
//      issue, L2 latency fully hidden).
// One extraction per mask (shared by both M1 consumers), flag-padded to 16
// slots (fma(w, 0.0) exact no-op); n>16 falls to an immediate-consume loop.
// W2 + rcW2 pair-interleaved in LDS (128 KB); readout hoisted to counts.
// ---------------------------------------------------------------------------

// Extract up to 16 ascending set-bit indices from the 128-bit mask (m0,m1);
// flag = 0 for exhausted slots. All values wave-uniform -> scalar pipe.
__device__ __forceinline__ void extract16(unsigned long long& m0,
                                          unsigned long long& m1,
                                          int* ks, float* fs) {
#pragma unroll
    for (int j = 0; j < 16; ++j) {
        const bool h0  = (m0 != 0ull);
        const bool h1  = (m1 != 0ull);
        const bool any = h0 | h1;
        unsigned long long mm = h0 ? m0 : m1;
        int k = (int)__ffsll((unsigned long long)mm) - 1;   // -1 if mm==0
        ks[j] = any ? (h0 ? k : k + 64) : 0;
        fs[j] = any ? 1.f : 0.f;
        unsigned long long cl = mm & (mm - 1ull);
        if (h0)      m0 = cl;
        else if (h1) m1 = cl;
    }
}

__global__ __launch_bounds__(64, 1) void recurrent(
    const float* __restrict__ H1,   const float* __restrict__ rcW1,
    const float* __restrict__ rcb1, const float* __restrict__ W2,
    const float* __restrict__ b2,   const float* __restrict__ rcW2,
    const float* __restrict__ rcb2, const float* __restrict__ W3,
    const float* __restrict__ b3,   float* __restrict__ out) {

    __shared__ float sW2[Hh * Hh];    // 64 KB, pair-interleaved
    __shared__ float sRc2[Hh * Hh];   // 64 KB, pair-interleaved
    __shared__ float scnt[Hh];

    const int lane = threadIdx.x;     // 0..63
    const int b    = blockIdx.x;

    // ---- stage W2, rcW2 pair-interleaved (float4 loads, b128 writes) ----
    // task: k = it>>4, quad p = (it&15)*4 -> lds floats k*128 + 2p .. 2p+7
    for (int it = lane; it < Hh * 16; it += 64) {
        int k = it >> 4, p = (it & 15) * 4;
        float4 a2 = *(const float4*)&W2 [k * Hh + p];
        float4 b2v = *(const float4*)&W2 [k * Hh + 64 + p];
        float4 ar = *(const float4*)&rcW2[k * Hh + p];
        float4 br = *(const float4*)&rcW2[k * Hh + 64 + p];
        float* d2 = &sW2 [k * Hh + 2 * p];
        float* dr = &sRc2[k * Hh + 2 * p];
        d2[0] = a2.x; d2[1] = b2v.x; d2[2] = a2.y; d2[3] = b2v.y;
        d2[4] = a2.z; d2[5] = b2v.z; d2[6] = a2.w; d2[7] = b2v.w;
        dr[0] = ar.x; dr[1] = br.x; dr[2] = ar.y; dr[3] = br.y;
        dr[4] = ar.z; dr[5] = br.z; dr[6] = ar.w; dr[7] = br.w;
    }
    __syncthreads();

    const float rcb1x = rcb1[lane], rcb1y = rcb1[lane + 64];
    const float bb2x  = b2[lane]      + rcb2[lane];
    const float bb2y  = b2[lane + 64] + rcb2[lane + 64];
    const float* __restrict__ h1p = H1 + (size_t)b * Tt * Hh;

    float v1x = 0.f, v1y = 0.f, v2x = 0.f, v2y = 0.f;
    float cntx = 0.f, cnty = 0.f;
    float u1gx = 0.f, u1gy = 0.f;     // rcW1 gather result (prev step)
    float u2gx = 0.f, u2gy = 0.f;     // rcW2 gather result (prev step)

    float h1x = h1p[lane], h1y = h1p[lane + 64];

    for (int t = 0; t < Tt; ++t) {
        // ---- LIF 1 ----
        const float u1xv = h1x + rcb1x + u1gx;
        const float u1yv = h1y + rcb1y + u1gy;
        v1x = v1x + (u1xv - v1x) * 0.5f;
        v1y = v1y + (u1yv - v1y) * 0.5f;
        const bool s1x = (v1x >= 1.0f);
        const bool s1y = (v1y >= 1.0f);
        if (s1x) v1x = 0.f;
        if (s1y) v1y = 0.f;
        unsigned long long a0 = __ballot((int)s1x);
        unsigned long long a1 = __ballot((int)s1y);

        // prefetch next h1 pair (vmcnt; drained together with rcW1 later)
        const int tn = (t + 1 < Tt) ? (t + 1) : (Tt - 1);
        const float h1xn = h1p[(size_t)tn * Hh + lane];
        const float h1yn = h1p[(size_t)tn * Hh + lane + 64];

        // ---- M1 batch 0: extract once, feed BOTH W2 (LDS) and rcW1 ----
        int ks1[16]; float fs1[16];
        extract16(a0, a1, ks1, fs1);

        float2 w2v[16];
        float  r1a[16], r1b[16];
#pragma unroll
        for (int j = 0; j < 16; ++j) {
            w2v[j] = *(const float2*)(sW2 + ks1[j] * Hh + 2 * lane);
            const float* p = rcW1 + ks1[j] * Hh;
            r1a[j] = p[lane];
            r1b[j] = p[lane + 64];
        }
        // W2 FMAs (lgkm wait only — rcW1 regs not touched yet)
        float px0 = 0.f, px1 = 0.f, py0 = 0.f, py1 = 0.f;
#pragma unroll
        for (int j = 0; j < 16; j += 2) {
            px0 = fmaf(w2v[j].x,     fs1[j],     px0);
            py0 = fmaf(w2v[j].y,     fs1[j],     py0);
            px1 = fmaf(w2v[j + 1].x, fs1[j + 1], px1);
            py1 = fmaf(w2v[j + 1].y, fs1[j + 1], py1);
        }
        float uW2x = px0 + px1, uW2y = py0 + py1;
        float u1gxn = 0.f, u1gyn = 0.f;

        // rare slow path: n1 > 16 (immediate consume)
        while (a0 | a1) {
            int kse[16]; float fse[16];
            extract16(a0, a1, kse, fse);
#pragma unroll
            for (int j = 0; j < 16; ++j) {
                float2 w = *(const float2*)(sW2 + kse[j] * Hh + 2 * lane);
                uW2x = fmaf(w.x, fse[j], uW2x);
                uW2y = fmaf(w.y, fse[j], uW2y);
                const float* p = rcW1 + kse[j] * Hh;
                u1gxn = fmaf(p[lane],      fse[j], u1gxn);
                u1gyn = fmaf(p[lane + 64], fse[j], u1gyn);
            }
        }

        // ---- LIF 2 ----
        const float u2xv = bb2x + uW2x + u2gx;
        const float u2yv = bb2y + uW2y + u2gy;
        v2x = v2x + (u2xv - v2x) * 0.5f;
        v2y = v2y + (u2yv - v2y) * 0.5f;
        const bool s2x = (v2x >= 1.0f);
        const bool s2y = (v2y >= 1.0f);
        if (s2x) v2x = 0.f;
        if (s2y) v2y = 0.f;
        cntx += s2x ? 1.f : 0.f;
        cnty += s2y ? 1.f : 0.f;
        unsigned long long b0 = __ballot((int)s2x);
        unsigned long long b1m = __ballot((int)s2y);

        // ---- M2: rcW2 gather (LDS), all batches immediate ----
        float u2gxn = 0.f, u2gyn = 0.f;
        while (b0 | b1m) {
            int ks2[16]; float fs2[16];
            extract16(b0, b1m, ks2, fs2);
            float2 w2[16];
#pragma unroll
            for (int j = 0; j < 16; ++j)
                w2[j] = *(const float2*)(sRc2 + ks2[j] * Hh + 2 * lane);
            float qx0 = 0.f, qx1 = 0.f, qy0 = 0.f, qy1 = 0.f;
#pragma unroll
            for (int j = 0; j < 16; j += 2) {
                qx0 = fmaf(w2[j].x,     fs2[j],     qx0);
                qy0 = fmaf(w2[j].y,     fs2[j],     qy0);
                qx1 = fmaf(w2[j + 1].x, fs2[j + 1], qx1);
                qy1 = fmaf(w2[j + 1].y, fs2[j + 1], qy1);
            }
            u2gxn += (qx0 + qx1);
            u2gyn += (qy0 + qy1);
        }

        // ---- consume deferred rcW1 batch 0 (vmcnt wait lands here) ----
        float gx0 = 0.f, gx1 = 0.f, gy0 = 0.f, gy1 = 0.f;
#pragma unroll
        for (int j = 0; j < 16; j += 2) {
            gx0 = fmaf(r1a[j],     fs1[j],     gx0);
            gy0 = fmaf(r1b[j],     fs1[j],     gy0);
            gx1 = fmaf(r1a[j + 1], fs1[j + 1], gx1);
            gy1 = fmaf(r1b[j + 1], fs1[j + 1], gy1);
        }
        u1gx = u1gxn + (gx0 + gx1);
        u1gy = u1gyn + (gy0 + gy1);
        u2gx = u2gxn;
        u2gy = u2gyn;

        h1x = h1xn;
        h1y = h1yn;
    }

    // ---- readout: out[b] = cnt2 @ W3 + T*b3 ----
    scnt[lane]      = cntx;
    scnt[lane + 64] = cnty;
    __syncthreads();
    if (lane < DOUT) {
        float o = (float)Tt * b3[lane];
#pragma unroll 8
        for (int k = 0; k < Hh; ++k) o += scnt[k] * W3[k * DOUT + lane];
        out[b * DOUT + lane] = o;
    }
}

// ---------------------------------------------------------------------------
extern "C" void kernel_launch(void* const* d_in, const int* in_sizes, int n_in,
                              void* d_out, int out_size, void* d_ws, size_t ws_size,
                              hipStream_t stream) {
    const float* x    = (const float*)d_in[0];
    const float* W1   = (const float*)d_in[1];
    const float* b1   = (const float*)d_in[2];
    const float* rcW1 = (const float*)d_in[3];
    const float* rcb1 = (const float*)d_in[4];
    const float* W2   = (const float*)d_in[5];
    const float* b2   = (const float*)d_in[6];
    const float* rcW2 = (const float*)d_in[7];
    const float* rcb2 = (const float*)d_in[8];
    const float* W3   = (const float*)d_in[9];
    const float* b3   = (const float*)d_in[10];

    float* out = (float*)d_out;
    float* H1  = (float*)d_ws;   // 64000 x 128 f32 = 32.77 MB

    gemm_h1<<<(Bb * Tt) / BM, 256, 0, stream>>>(x, W1, b1, H1);
    recurrent<<<Bb, 64, 0, stream>>>(H1, rcW1, rcb1, W2, b2, rcW2, rcb2, W3,
                                     b3, out);
}

// Round 5
// 451.251 us; speedup vs baseline: 2.0015x; 2.0015x over previous
//
#include <hip/hip_runtime.h>
#include <cstdint>
#include <cstddef>

// Problem constants (match reference setup_inputs)
#define Bb   256
#define Tt   250
#define DIN  700
#define Hh   128
#define DOUT 20

// ---------------------------------------------------------------------------
// Phase 1: H1[b*T+t][h] = x[b][t][:] @ W1[:,h] + b1[h]
// M=64000, K=700, N=128. 128x128 tile, BK=20, 256 threads, 8x8 micro-tile.
// (unchanged from R3: 215 us, isolated so the recurrent change is attributable)
// ---------------------------------------------------------------------------
constexpr int BM  = 128;
constexpr int BK  = 20;
constexpr int BN  = 128;
constexpr int BMP = BM + 4;   // padded row length for Ast (staging writes)

__device__ __forceinline__ int bswz(int g) { return g ^ (g >> 3); }

__global__ __launch_bounds__(256, 2) void gemm_h1(const float* __restrict__ x,
                                                  const float* __restrict__ W1,
                                                  const float* __restrict__ b1,
                                                  float* __restrict__ H1) {
    __shared__ float Ast[BK][BMP];  // x tile, TRANSPOSED: Ast[k][m], padded
    __shared__ float Bs[BK][BN];    // W1 tile, column-group swizzled

    const int tid = threadIdx.x;
    const int tx  = tid & 15;       // col group: cols tx*8 .. +7
    const int ty  = tid >> 4;       // row group: rows ty*8 .. +7
    const int m0  = blockIdx.x * BM;

    const int c0 = bswz(tx * 2) * 4;
    const int c1 = bswz(tx * 2 + 1) * 4;

    float acc[8][8];
#pragma unroll
    for (int r = 0; r < 8; ++r)
#pragma unroll
        for (int c = 0; c < 8; ++c) acc[r][c] = 0.f;

    for (int k0 = 0; k0 < DIN; k0 += BK) {
#pragma unroll
        for (int idx = tid; idx < 640; idx += 256) {
            int row = idx / 5;
            int kq  = (idx - row * 5) * 4;
            const float4 v =
                *(const float4*)&x[(size_t)(m0 + row) * DIN + (k0 + kq)];
            Ast[kq + 0][row] = v.x;
            Ast[kq + 1][row] = v.y;
            Ast[kq + 2][row] = v.z;
            Ast[kq + 3][row] = v.w;
        }
#pragma unroll
        for (int idx = tid; idx < 640; idx += 256) {
            int kr = idx >> 5;
            int g  = idx & 31;
            *(float4*)&Bs[kr][bswz(g) * 4] =
                *(const float4*)&W1[(size_t)(k0 + kr) * BN + g * 4];
        }
        __syncthreads();

#pragma unroll
        for (int kk = 0; kk < BK; ++kk) {
            float a[8], bv[8];
            *(float4*)&a[0]  = *(const float4*)&Ast[kk][ty * 8];
            *(float4*)&a[4]  = *(const float4*)&Ast[kk][ty * 8 + 4];
            *(float4*)&bv[0] = *(const float4*)&Bs[kk][c0];
            *(float4*)&bv[4] = *(const float4*)&Bs[kk][c1];
#pragma unroll
            for (int r = 0; r < 8; ++r)
#pragma unroll
                for (int c = 0; c < 8; ++c)
                    acc[r][c] = fmaf(a[r], bv[c], acc[r][c]);
        }
        __syncthreads();
    }

    float bb[8];
#pragma unroll
    for (int c = 0; c < 8; ++c) bb[c] = b1[tx * 8 + c];

#pragma unroll
    for (int r = 0; r < 8; ++r) {
        size_t row = (size_t)(m0 + ty * 8 + r);
        float4 o0, o1;
        o0.x = acc[r][0] + bb[0]; o0.y = acc[r][1] + bb[1];
        o0.z = acc[r][2] + bb[2]; o0.w = acc[r][3] + bb[3];
        o1.x = acc[r][4] + bb[4]; o1.y = acc[r][5] + bb[5];
        o1.z = acc[r][6] + bb[6]; o1.w = acc[r][7] + bb[7];
        *(float4*)&H1[row * Hh + tx * 8]     = o0;
        *(float4*)&H1[row * Hh + tx * 8 + 4] = o1;
    }
}

// ---------------------------------------------------------------------------
// Phase 2: recurrence, wave-autonomous, latency-path-minimized.
// 256 blocks x 64 threads (1 wave = 1 batch row), lane owns units
// {lane, lane+64}. Firing rates are tiny (P~0.1%/unit/step), so:
//  - gathers are per-bit serial walks guarded by `if (mask)` -> zero cost
//    on empty steps (the common case); ascending-k order (m0 bits then m1)
//    keeps summation order identical to the dense reference (adding exact
//    zeros is exact).
//  - weights gathered straight from global (192 KB total, L2-resident);
//    no LDS staging (R4's 128 KB bought nothing and cost a lot).
//  - h1 prefetched through a 4-slot register pipeline (issue t+4, consume t):
//    ~4 loop bodies between issue and use hides even HBM-miss latency (~900
//    cyc), which was the structurally-exposed stall in R1-R4.
// Readout hoisted: out = cnt2 @ W3 + T*b3.
// ---------------------------------------------------------------------------
__global__ __launch_bounds__(64) void recurrent(
    const float* __restrict__ H1,   const float* __restrict__ rcW1,
    const float* __restrict__ rcb1, const float* __restrict__ W2,
    const float* __restrict__ b2,   const float* __restrict__ rcW2,
    const float* __restrict__ rcb2, const float* __restrict__ W3,
    const float* __restrict__ b3,   float* __restrict__ out) {

    __shared__ float scnt[Hh];

    const int lane = threadIdx.x;     // 0..63
    const int b    = blockIdx.x;

    const float rcb1x = rcb1[lane], rcb1y = rcb1[lane + 64];
    const float bb2x  = b2[lane]      + rcb2[lane];
    const float bb2y  = b2[lane + 64] + rcb2[lane + 64];
    const float* __restrict__ h1p = H1 + (size_t)b * Tt * Hh;

    float v1x = 0.f, v1y = 0.f, v2x = 0.f, v2y = 0.f;
    float cntx = 0.f, cnty = 0.f;
    float u1gx = 0.f, u1gy = 0.f;     // rcW1 gather result (prev step)
    float u2gx = 0.f, u2gy = 0.f;     // rcW2 gather result (prev step)

    // 4-deep h1 prefetch pipeline (slot j holds step t with t%4==j)
    float h1xs[4], h1ys[4];
#pragma unroll
    for (int j = 0; j < 4; ++j) {
        h1xs[j] = h1p[j * Hh + lane];
        h1ys[j] = h1p[j * Hh + lane + 64];
    }

#define STEP(T, J)                                                            \
    {                                                                         \
        const int t_ = (T);                                                   \
        /* ---- LIF 1 (consume slot J, then refill it for t+4) ---- */        \
        const float u1xv = h1xs[J] + rcb1x + u1gx;                            \
        const float u1yv = h1ys[J] + rcb1y + u1gy;                            \
        int tp = t_ + 4; tp = (tp < Tt) ? tp : (Tt - 1);                      \
        h1xs[J] = h1p[(size_t)tp * Hh + lane];                                \
        h1ys[J] = h1p[(size_t)tp * Hh + lane + 64];                           \
        v1x = v1x + (u1xv - v1x) * 0.5f;                                      \
        v1y = v1y + (u1yv - v1y) * 0.5f;                                      \
        const bool s1x = (v1x >= 1.0f);                                       \
        const bool s1y = (v1y >= 1.0f);                                       \
        if (s1x) v1x = 0.f;                                                   \
        if (s1y) v1y = 0.f;                                                   \
        const unsigned long long a0 = __ballot((int)s1x);                     \
        const unsigned long long a1 = __ballot((int)s1y);                     \
        /* ---- layer-1 spike fanout: W2 (this step) + rcW1 (next) ---- */    \
        float uW2x = 0.f, uW2y = 0.f, g1x = 0.f, g1y = 0.f;                   \
        if (a0 | a1) {                                                        \
            unsigned long long m = a0;                                        \
            int base = 0;                                                     \
            for (int hlf = 0; hlf < 2; ++hlf) {                               \
                while (m) {                                                   \
                    const int k = (int)__ffsll(m) - 1 + base;                 \
                    m &= (m - 1ull);                                          \
                    const float* __restrict__ pw = W2 + k * Hh;               \
                    const float* __restrict__ pr = rcW1 + k * Hh;             \
                    uW2x += pw[lane]; uW2y += pw[lane + 64];                  \
                    g1x  += pr[lane]; g1y  += pr[lane + 64];                  \
                }                                                             \
                m = a1; base = 64;                                            \
            }                                                                 \
        }                                                                     \
        u1gx = g1x; u1gy = g1y;                                               \
        /* ---- LIF 2 ---- */                                                 \
        const float u2xv = bb2x + uW2x + u2gx;                                \
        const float u2yv = bb2y + uW2y + u2gy;                                \
        v2x = v2x + (u2xv - v2x) * 0.5f;                                      \
        v2y = v2y + (u2yv - v2y) * 0.5f;                                      \
        const bool s2x = (v2x >= 1.0f);                                       \
        const bool s2y = (v2y >= 1.0f);                                       \
        if (s2x) v2x = 0.f;                                                   \
        if (s2y) v2y = 0.f;                                                   \
        cntx += s2x ? 1.f : 0.f;                                              \
        cnty += s2y ? 1.f : 0.f;                                              \
        const unsigned long long c0m = __ballot((int)s2x);                    \
        const unsigned long long c1m = __ballot((int)s2y);                    \
        float g2x = 0.f, g2y = 0.f;                                           \
        if (c0m | c1m) {                                                      \
            unsigned long long m = c0m;                                       \
            int base = 0;                                                     \
            for (int hlf = 0; hlf < 2; ++hlf) {                               \
                while (m) {                                                   \
                    const int k = (int)__ffsll(m) - 1 + base;                 \
                    m &= (m - 1ull);                                          \
                    const float* __restrict__ pr = rcW2 + k * Hh;             \
                    g2x += pr[lane]; g2y += pr[lane + 64];                    \
                }                                                             \
                m = c1m; base = 64;                                           \
            }                                                                 \
        }                                                                     \
        u2gx = g2x; u2gy = g2y;                                               \
    }

    // 250 = 4*62 + 2: unrolled main loop keeps slot index J compile-time
    for (int tb = 0; tb < 62; ++tb) {
        const int t0 = tb * 4;
        STEP(t0 + 0, 0)
        STEP(t0 + 1, 1)
        STEP(t0 + 2, 2)
        STEP(t0 + 3, 3)
    }
    STEP(248, 0)
    STEP(249, 1)
#undef STEP

    // ---- readout: out[b] = cnt2 @ W3 + T*b3 ----
    scnt[lane]      = cntx;
    scnt[lane + 64] = cnty;
    __syncthreads();
    if (lane < DOUT) {
        float o = (float)Tt * b3[lane];
#pragma unroll 8
        for (int k = 0; k < Hh; ++k) o += scnt[k] * W3[k * DOUT + lane];
        out[b * DOUT + lane] = o;
    }
}

// ---------------------------------------------------------------------------
extern "C" void kernel_launch(void* const* d_in, const int* in_sizes, int n_in,
                              void* d_out, int out_size, void* d_ws, size_t ws_size,
                              hipStream_t stream) {
    const float* x    = (const float*)d_in[0];
    const float* W1   = (const float*)d_in[1];
    const float* b1   = (const float*)d_in[2];
    const float* rcW1 = (const float*)d_in[3];
    const float* rcb1 = (const float*)d_in[4];
    const float* W2   = (const float*)d_in[5];
    const float* b2   = (const float*)d_in[6];
    const float* rcW2 = (const float*)d_in[7];
    const float* rcb2 = (const float*)d_in[8];
    const float* W3   = (const float*)d_in[9];
    const float* b3   = (const float*)d_in[10];

    float* out = (float*)d_out;
    float* H1  = (float*)d_ws;   // 64000 x 128 f32 = 32.77 MB

    gemm_h1<<<(Bb * Tt) / BM, 256, 0, stream>>>(x, W1, b1, H1);
    recurrent<<<Bb, 64, 0, stream>>>(H1, rcW1, rcb1, W2, b2, rcW2, rcb2, W3,
                                     b3, out);
}